// Round 18
// baseline (2699.796 us; speedup 1.0000x reference)
//
#include <hip/hip_runtime.h>
#include <stdint.h>

#define T_STEPS 100
#define BATCH   256
#define N_IN    2048
#define N_H     1024
#define N_OUT   10
#define M_TOT   (T_STEPS * BATCH)   // 25600
#define KC      384                 // OpenBLAS SGEMM_DEFAULT_Q (Haswell/Zen)

// ---------------------------------------------------------------------------
// GEMM1 panel pass (one dispatch per KC panel; 6 total) — R16 structure +
// hoisted global pointers + register-prefetch dbuf staging (1 barrier/k0).
// Bit-exact contract (R9/R14/R16-verified): per C element each panel is a
// k-ascending FMA register chain from 0; joins are one f32 add per panel
// boundary in pass order (C RMW between dispatches); bias after last.
// Tile 128m x 64n, BK=16, 256 threads, 8x4 microtile, target <=64 VGPR ->
// __launch_bounds__(256,8) = 32 waves/CU.
// XCD map: xcd=id&7 owns an m-strip; 16 n-tiles of an m-tile consecutive.
// ---------------------------------------------------------------------------
__global__ __launch_bounds__(256, 8) void gemm1_panel(
    const float* __restrict__ A, const float* __restrict__ Bm,
    const float* __restrict__ bias, float* __restrict__ C,
    int ks, int klen, int first, int last) {
  __shared__ float As[2][16][132];   // [buf][k][m], +4 pad  (16.9 KB)
  __shared__ float Bs[2][16][68];    // [buf][k][n], +4 pad  ( 8.7 KB)
  const int tid = threadIdx.x;
  const int id = blockIdx.x;
  const int xcd = id & 7;
  const int j = id >> 3;               // 0..399 sequential per XCD
  const int m0 = (xcd * 25 + (j >> 4)) * 128;
  const int n0 = (j & 15) * 64;
  const int tx = tid & 15;        // col group (4 cols)
  const int ty = tid >> 4;        // row group (8 rows)
  const int lrow = tid >> 2;      // 0..63
  const int lc4 = (tid & 3) * 4;  // 0,4,8,12

  // hoisted per-thread global pointers (stride N_IN floats per row)
  const float* pA0 = &A[(size_t)(m0 + lrow) * N_IN + ks + lc4];
  const float* pA1 = &A[(size_t)(m0 + lrow + 64) * N_IN + ks + lc4];
  const float* pB  = &Bm[(size_t)(n0 + lrow) * N_IN + ks + lc4];

  float acc[8][4];
#pragma unroll
  for (int i = 0; i < 8; i++)
#pragma unroll
    for (int j2 = 0; j2 < 4; j2++) acc[i][j2] = 0.f;

  // prologue: load step 0, write buffer 0
  float4 rA0 = *(const float4*)(pA0);
  float4 rA1 = *(const float4*)(pA1);
  float4 rB  = *(const float4*)(pB);
  As[0][lc4 + 0][lrow] = rA0.x; As[0][lc4 + 1][lrow] = rA0.y;
  As[0][lc4 + 2][lrow] = rA0.z; As[0][lc4 + 3][lrow] = rA0.w;
  As[0][lc4 + 0][lrow + 64] = rA1.x; As[0][lc4 + 1][lrow + 64] = rA1.y;
  As[0][lc4 + 2][lrow + 64] = rA1.z; As[0][lc4 + 3][lrow + 64] = rA1.w;
  Bs[0][lc4 + 0][lrow] = rB.x; Bs[0][lc4 + 1][lrow] = rB.y;
  Bs[0][lc4 + 2][lrow] = rB.z; Bs[0][lc4 + 3][lrow] = rB.w;
  __syncthreads();

  const int nsteps = klen / 16;   // 24
  int cur = 0;
  for (int s = 0; s < nsteps; ++s) {
    // issue next step's loads immediately (retire under this step's FMAs)
    if (s + 1 < nsteps) {
      pA0 += 16; pA1 += 16; pB += 16;
      rA0 = *(const float4*)(pA0);
      rA1 = *(const float4*)(pA1);
      rB  = *(const float4*)(pB);
    }
    // compute on current buffer
#pragma unroll
    for (int k = 0; k < 16; k++) {
      float a[8], b[4];
      *(float4*)&a[0] = *(const float4*)&As[cur][k][ty * 8];
      *(float4*)&a[4] = *(const float4*)&As[cur][k][ty * 8 + 4];
      *(float4*)&b[0] = *(const float4*)&Bs[cur][k][tx * 4];
#pragma unroll
      for (int i = 0; i < 8; i++)
#pragma unroll
        for (int j2 = 0; j2 < 4; j2++)
          acc[i][j2] = __builtin_fmaf(a[i], b[j2], acc[i][j2]);
    }
    // write prefetched tile into idle buffer; single barrier per step
    if (s + 1 < nsteps) {
      const int nxt = cur ^ 1;
      As[nxt][lc4 + 0][lrow] = rA0.x; As[nxt][lc4 + 1][lrow] = rA0.y;
      As[nxt][lc4 + 2][lrow] = rA0.z; As[nxt][lc4 + 3][lrow] = rA0.w;
      As[nxt][lc4 + 0][lrow + 64] = rA1.x; As[nxt][lc4 + 1][lrow + 64] = rA1.y;
      As[nxt][lc4 + 2][lrow + 64] = rA1.z; As[nxt][lc4 + 3][lrow + 64] = rA1.w;
      Bs[nxt][lc4 + 0][lrow] = rB.x; Bs[nxt][lc4 + 1][lrow] = rB.y;
      Bs[nxt][lc4 + 2][lrow] = rB.z; Bs[nxt][lc4 + 3][lrow] = rB.w;
      __syncthreads();
      cur = nxt;
    }
  }
  // epilogue: join with previous panels (one add), bias after last panel
#pragma unroll
  for (int i = 0; i < 8; i++) {
    const int m = m0 + ty * 8 + i;
    const int n1 = n0 + tx * 4;
    float4* cp = (float4*)&C[(size_t)m * N_H + n1];
    float4 v;
    v.x = acc[i][0]; v.y = acc[i][1]; v.z = acc[i][2]; v.w = acc[i][3];
    if (!first) {
      const float4 o = *cp;
      v.x = __fadd_rn(o.x, v.x); v.y = __fadd_rn(o.y, v.y);
      v.z = __fadd_rn(o.z, v.z); v.w = __fadd_rn(o.w, v.w);
    }
    if (last) {
      v.x = __fadd_rn(v.x, bias[n1 + 0]); v.y = __fadd_rn(v.y, bias[n1 + 1]);
      v.z = __fadd_rn(v.z, bias[n1 + 2]); v.w = __fadd_rn(v.w, bias[n1 + 3]);
    }
    *cp = v;
  }
}

// ---------------------------------------------------------------------------
// Scan1: strict numpy op order (no fma): mem = ((0.9*mem) + cur) - reset.
// Spikes -> packed 64-bit ballot masks.
// ---------------------------------------------------------------------------
__global__ __launch_bounds__(256) void scan1_kernel(
    const float* __restrict__ cur1, unsigned long long* __restrict__ spkbits) {
  const int b = blockIdx.x >> 2;
  const int h = (blockIdx.x & 3) * 256 + threadIdx.x;
  const int lane = threadIdx.x & 63;
  const int word = h >> 6;  // 0..15
  float mem = 0.f;
  for (int t = 0; t < T_STEPS; ++t) {
    const float c = cur1[((size_t)t * BATCH + b) * N_H + h];
    const float reset = (mem > 1.0f) ? 1.0f : 0.0f;   // previous mem
    mem = __fsub_rn(__fadd_rn(__fmul_rn(0.9f, mem), c), reset);
    const unsigned long long msk = __ballot(mem > 1.0f);
    if (lane == 0) spkbits[((size_t)t * BATCH + b) * 16 + word] = msk;
  }
}

// ---------------------------------------------------------------------------
// cur2 (parallel over t,b,o): 3-panel k-ascending FMA chains —
// s1=[0,384), s2=[384,768), s3=[768,1024); cur2 = ((s1+s2)+s3) + b2[o].
// ---------------------------------------------------------------------------
__global__ __launch_bounds__(256) void cur2_kernel(
    const unsigned long long* __restrict__ spkbits,
    const float* __restrict__ W2, const float* __restrict__ b2,
    float* __restrict__ cur2) {
  const int g = blockIdx.x * 256 + threadIdx.x;   // ((t*256)+b)*10 + o
  const int tb = g / N_OUT;                       // t*256 + b
  const int o = g - tb * N_OUT;
  unsigned long long w[16];
#pragma unroll
  for (int i = 0; i < 16; i++) w[i] = spkbits[(size_t)tb * 16 + i];
  const float* W2o = &W2[(size_t)o * N_H];
  float s1 = 0.f, s2 = 0.f, s3 = 0.f;
#pragma unroll 8
  for (int h = 0; h < KC; ++h) {
    const float spk = ((w[h >> 6] >> (h & 63)) & 1ull) ? 1.0f : 0.0f;
    s1 = __builtin_fmaf(spk, W2o[h], s1);
  }
#pragma unroll 8
  for (int h = KC; h < 2 * KC; ++h) {
    const float spk = ((w[h >> 6] >> (h & 63)) & 1ull) ? 1.0f : 0.0f;
    s2 = __builtin_fmaf(spk, W2o[h], s2);
  }
#pragma unroll 8
  for (int h = 2 * KC; h < N_H; ++h) {
    const float spk = ((w[h >> 6] >> (h & 63)) & 1ull) ? 1.0f : 0.0f;
    s3 = __builtin_fmaf(spk, W2o[h], s3);
  }
  cur2[g] = __fadd_rn(__fadd_rn(__fadd_rn(s1, s2), s3), b2[o]);
}

// ---------------------------------------------------------------------------
// Scan2: strict mem2 scan over t per (b,o); writes spk2 + final mem2 (f32).
// ---------------------------------------------------------------------------
__global__ __launch_bounds__(256) void scan2_kernel(
    const float* __restrict__ cur2, float* __restrict__ out) {
  const int g = blockIdx.x * 256 + threadIdx.x;   // b*10 + o
  float m = 0.f;
  for (int t = 0; t < T_STEPS; ++t) {
    const float c = cur2[(size_t)t * (BATCH * N_OUT) + g];
    const float reset = (m > 1.0f) ? 1.0f : 0.0f;   // previous mem2
    m = __fsub_rn(__fadd_rn(__fmul_rn(0.9f, m), c), reset);
    out[(size_t)t * (BATCH * N_OUT) + g] = (m > 1.0f) ? 1.0f : 0.0f;
  }
  out[(size_t)T_STEPS * (BATCH * N_OUT) + g] = m;
}

// ---------------------------------------------------------------------------
extern "C" void kernel_launch(void* const* d_in, const int* in_sizes, int n_in,
                              void* d_out, int out_size, void* d_ws, size_t ws_size,
                              hipStream_t stream) {
  const float* x  = (const float*)d_in[0];   // [T, B, N_IN]  f32
  const float* W1 = (const float*)d_in[1];   // [N_H, N_IN]   f32
  const float* b1 = (const float*)d_in[2];   // [N_H]         f32
  const float* W2 = (const float*)d_in[3];   // [N_OUT, N_H]  f32
  const float* b2 = (const float*)d_in[4];   // [N_OUT]       f32
  float* out = (float*)d_out;  // f32: spk2[100,256,10] ++ mem2[256,10]

  // ws: cur1 f32 (104.9MB) | bits (3.3MB) | cur2 f32 (1.02MB)
  char* p = (char*)d_ws;
  float* cur1 = (float*)p;                           p += (size_t)M_TOT * N_H * 4;
  unsigned long long* bits = (unsigned long long*)p; p += (size_t)M_TOT * 16 * 8;
  float* cur2 = (float*)p;

  const int nblk = (M_TOT / 128) * (N_H / 64);   // 3200
  for (int ks = 0; ks < N_IN; ks += KC) {
    const int klen = (ks + KC <= N_IN) ? KC : (N_IN - ks);
    gemm1_panel<<<nblk, 256, 0, stream>>>(x, W1, b1, cur1, ks, klen,
                                          ks == 0 ? 1 : 0,
                                          (ks + klen == N_IN) ? 1 : 0);
  }
  scan1_kernel<<<BATCH * (N_H / 256), 256, 0, stream>>>(cur1, bits);
  cur2_kernel<<<(M_TOT * N_OUT) / 256, 256, 0, stream>>>(bits, W2, b2, cur2);
  scan2_kernel<<<(BATCH * N_OUT) / 256, 256, 0, stream>>>(cur2, out);
}

// Round 19
// 1557.227 us; speedup vs baseline: 1.7337x; 1.7337x over previous
//
#include <hip/hip_runtime.h>
#include <stdint.h>

#define T_STEPS 100
#define BATCH   256
#define N_IN    2048
#define N_H     1024
#define N_OUT   10
#define M_TOT   (T_STEPS * BATCH)   // 25600
#define KC      384                 // OpenBLAS SGEMM_DEFAULT_Q (Haswell/Zen)

// ---------------------------------------------------------------------------
// GEMM1 panel pass (one dispatch per KC panel; 6 total).
// Bit-exact contract (R9/R14/R16-verified): per C element each panel is a
// k-ascending FMA register chain from 0; joins are one f32 add per panel
// boundary in pass order (C RMW between dispatches); bias after last.
// Tile 128m x 128n, BK=16, 512 threads, 8x4 microtile -> acc 32 VGPR;
// __launch_bounds__(512,8): 4 blocks/CU = 32 waves/CU, VGPR cap 64.
// Staging per thread per step: 1 A-float4 + 1 B-float4 + 8 ds_write_b32
// (half of R16's per-FMA staging cost).
// XCD map: xcd=id&7 owns an m-strip; 8 n-tiles of an m-tile consecutive.
// ---------------------------------------------------------------------------
__global__ __launch_bounds__(512, 8) void gemm1_panel(
    const float* __restrict__ A, const float* __restrict__ Bm,
    const float* __restrict__ bias, float* __restrict__ C,
    int ks, int klen, int first, int last) {
  __shared__ float As[16][132];   // [k][m], +4 pad
  __shared__ float Bs[16][132];   // [k][n], +4 pad
  const int tid = threadIdx.x;
  const int id = blockIdx.x;
  const int xcd = id & 7;
  const int j = id >> 3;               // 0..199 sequential per XCD
  const int m0 = (xcd * 25 + (j >> 3)) * 128;
  const int n0 = (j & 7) * 128;
  const int tx = tid & 31;        // col group (4 cols)
  const int ty = tid >> 5;        // row group (8 rows)
  const int lrow = tid >> 2;      // 0..127
  const int lc4 = (tid & 3) * 4;  // 0,4,8,12

  // hoisted per-thread global pointers
  const float* pA = &A[(size_t)(m0 + lrow) * N_IN + ks + lc4];
  const float* pB = &Bm[(size_t)(n0 + lrow) * N_IN + ks + lc4];

  float acc[8][4];
#pragma unroll
  for (int i = 0; i < 8; i++)
#pragma unroll
    for (int j2 = 0; j2 < 4; j2++) acc[i][j2] = 0.f;

  for (int kk = 0; kk < klen; kk += 16) {
    // stage A tile (128x16) and B tile (128x16): 1 float4 each per thread
    const float4 av = *(const float4*)(pA + kk);
    const float4 bv = *(const float4*)(pB + kk);
    As[lc4 + 0][lrow] = av.x; As[lc4 + 1][lrow] = av.y;
    As[lc4 + 2][lrow] = av.z; As[lc4 + 3][lrow] = av.w;
    Bs[lc4 + 0][lrow] = bv.x; Bs[lc4 + 1][lrow] = bv.y;
    Bs[lc4 + 2][lrow] = bv.z; Bs[lc4 + 3][lrow] = bv.w;
    __syncthreads();
#pragma unroll
    for (int k = 0; k < 16; k++) {
      float a[8], b[4];
      *(float4*)&a[0] = *(const float4*)&As[k][ty * 8];
      *(float4*)&a[4] = *(const float4*)&As[k][ty * 8 + 4];
      *(float4*)&b[0] = *(const float4*)&Bs[k][tx * 4];
#pragma unroll
      for (int i = 0; i < 8; i++)
#pragma unroll
        for (int j2 = 0; j2 < 4; j2++)
          acc[i][j2] = __builtin_fmaf(a[i], b[j2], acc[i][j2]);
    }
    __syncthreads();
  }
  // epilogue: join with previous panels (one add), bias after last panel
#pragma unroll
  for (int i = 0; i < 8; i++) {
    const int m = m0 + ty * 8 + i;
    const int n1 = n0 + tx * 4;
    float4* cp = (float4*)&C[(size_t)m * N_H + n1];
    float4 v;
    v.x = acc[i][0]; v.y = acc[i][1]; v.z = acc[i][2]; v.w = acc[i][3];
    if (!first) {
      const float4 o = *cp;
      v.x = __fadd_rn(o.x, v.x); v.y = __fadd_rn(o.y, v.y);
      v.z = __fadd_rn(o.z, v.z); v.w = __fadd_rn(o.w, v.w);
    }
    if (last) {
      v.x = __fadd_rn(v.x, bias[n1 + 0]); v.y = __fadd_rn(v.y, bias[n1 + 1]);
      v.z = __fadd_rn(v.z, bias[n1 + 2]); v.w = __fadd_rn(v.w, bias[n1 + 3]);
    }
    *cp = v;
  }
}

// ---------------------------------------------------------------------------
// Scan1: strict numpy op order (no fma): mem = ((0.9*mem) + cur) - reset.
// Spikes -> packed 64-bit ballot masks.
// ---------------------------------------------------------------------------
__global__ __launch_bounds__(256) void scan1_kernel(
    const float* __restrict__ cur1, unsigned long long* __restrict__ spkbits) {
  const int b = blockIdx.x >> 2;
  const int h = (blockIdx.x & 3) * 256 + threadIdx.x;
  const int lane = threadIdx.x & 63;
  const int word = h >> 6;  // 0..15
  float mem = 0.f;
  for (int t = 0; t < T_STEPS; ++t) {
    const float c = cur1[((size_t)t * BATCH + b) * N_H + h];
    const float reset = (mem > 1.0f) ? 1.0f : 0.0f;   // previous mem
    mem = __fsub_rn(__fadd_rn(__fmul_rn(0.9f, mem), c), reset);
    const unsigned long long msk = __ballot(mem > 1.0f);
    if (lane == 0) spkbits[((size_t)t * BATCH + b) * 16 + word] = msk;
  }
}

// ---------------------------------------------------------------------------
// cur2 (parallel over t,b,o): 3-panel k-ascending FMA chains —
// s1=[0,384), s2=[384,768), s3=[768,1024); cur2 = ((s1+s2)+s3) + b2[o].
// ---------------------------------------------------------------------------
__global__ __launch_bounds__(256) void cur2_kernel(
    const unsigned long long* __restrict__ spkbits,
    const float* __restrict__ W2, const float* __restrict__ b2,
    float* __restrict__ cur2) {
  const int g = blockIdx.x * 256 + threadIdx.x;   // ((t*256)+b)*10 + o
  const int tb = g / N_OUT;                       // t*256 + b
  const int o = g - tb * N_OUT;
  unsigned long long w[16];
#pragma unroll
  for (int i = 0; i < 16; i++) w[i] = spkbits[(size_t)tb * 16 + i];
  const float* W2o = &W2[(size_t)o * N_H];
  float s1 = 0.f, s2 = 0.f, s3 = 0.f;
#pragma unroll 8
  for (int h = 0; h < KC; ++h) {
    const float spk = ((w[h >> 6] >> (h & 63)) & 1ull) ? 1.0f : 0.0f;
    s1 = __builtin_fmaf(spk, W2o[h], s1);
  }
#pragma unroll 8
  for (int h = KC; h < 2 * KC; ++h) {
    const float spk = ((w[h >> 6] >> (h & 63)) & 1ull) ? 1.0f : 0.0f;
    s2 = __builtin_fmaf(spk, W2o[h], s2);
  }
#pragma unroll 8
  for (int h = 2 * KC; h < N_H; ++h) {
    const float spk = ((w[h >> 6] >> (h & 63)) & 1ull) ? 1.0f : 0.0f;
    s3 = __builtin_fmaf(spk, W2o[h], s3);
  }
  cur2[g] = __fadd_rn(__fadd_rn(__fadd_rn(s1, s2), s3), b2[o]);
}

// ---------------------------------------------------------------------------
// Scan2: strict mem2 scan over t per (b,o); writes spk2 + final mem2 (f32).
// ---------------------------------------------------------------------------
__global__ __launch_bounds__(256) void scan2_kernel(
    const float* __restrict__ cur2, float* __restrict__ out) {
  const int g = blockIdx.x * 256 + threadIdx.x;   // b*10 + o
  float m = 0.f;
  for (int t = 0; t < T_STEPS; ++t) {
    const float c = cur2[(size_t)t * (BATCH * N_OUT) + g];
    const float reset = (m > 1.0f) ? 1.0f : 0.0f;   // previous mem2
    m = __fsub_rn(__fadd_rn(__fmul_rn(0.9f, m), c), reset);
    out[(size_t)t * (BATCH * N_OUT) + g] = (m > 1.0f) ? 1.0f : 0.0f;
  }
  out[(size_t)T_STEPS * (BATCH * N_OUT) + g] = m;
}

// ---------------------------------------------------------------------------
extern "C" void kernel_launch(void* const* d_in, const int* in_sizes, int n_in,
                              void* d_out, int out_size, void* d_ws, size_t ws_size,
                              hipStream_t stream) {
  const float* x  = (const float*)d_in[0];   // [T, B, N_IN]  f32
  const float* W1 = (const float*)d_in[1];   // [N_H, N_IN]   f32
  const float* b1 = (const float*)d_in[2];   // [N_H]         f32
  const float* W2 = (const float*)d_in[3];   // [N_OUT, N_H]  f32
  const float* b2 = (const float*)d_in[4];   // [N_OUT]       f32
  float* out = (float*)d_out;  // f32: spk2[100,256,10] ++ mem2[256,10]

  // ws: cur1 f32 (104.9MB) | bits (3.3MB) | cur2 f32 (1.02MB)
  char* p = (char*)d_ws;
  float* cur1 = (float*)p;                           p += (size_t)M_TOT * N_H * 4;
  unsigned long long* bits = (unsigned long long*)p; p += (size_t)M_TOT * 16 * 8;
  float* cur2 = (float*)p;

  const int nblk = (M_TOT / 128) * (N_H / 128);   // 1600
  for (int ks = 0; ks < N_IN; ks += KC) {
    const int klen = (ks + KC <= N_IN) ? KC : (N_IN - ks);
    gemm1_panel<<<nblk, 512, 0, stream>>>(x, W1, b1, cur1, ks, klen,
                                          ks == 0 ? 1 : 0,
                                          (ks + klen == N_IN) ? 1 : 0);
  }
  scan1_kernel<<<BATCH * (N_H / 256), 256, 0, stream>>>(cur1, bits);
  cur2_kernel<<<(M_TOT * N_OUT) / 256, 256, 0, stream>>>(bits, W2, b2, cur2);
  scan2_kernel<<<(BATCH * N_OUT) / 256, 256, 0, stream>>>(cur2, out);
}

// Round 20
// 1526.444 us; speedup vs baseline: 1.7687x; 1.0202x over previous
//
#include <hip/hip_runtime.h>
#include <stdint.h>

#define T_STEPS 100
#define BATCH   256
#define N_IN    2048
#define N_H     1024
#define N_OUT   10
#define M_TOT   (T_STEPS * BATCH)   // 25600
#define KC      384                 // OpenBLAS SGEMM_DEFAULT_Q (Haswell/Zen)

// ---------------------------------------------------------------------------
// GEMM1 panel pass (one dispatch per KC panel; 6 total).
// Bit-exact contract (R9/R14/R16/R19-verified): per C element each panel is a
// k-ascending FMA register chain from 0; joins are one f32 add per panel
// boundary in pass order (C RMW between dispatches); bias after last.
// Tile 128m x 128n, BK=32 (24 barriers/panel vs R19's 48), 512 threads,
// 8x4 microtile -> acc 32 VGPR; __launch_bounds__(512,8): 4 blocks/CU.
// XCD map: xcd=id&7 owns an m-strip; 8 n-tiles of an m-tile consecutive.
// ---------------------------------------------------------------------------
__global__ __launch_bounds__(512, 8) void gemm1_panel(
    const float* __restrict__ A, const float* __restrict__ Bm,
    const float* __restrict__ bias, float* __restrict__ C,
    int ks, int klen, int first, int last) {
  __shared__ float As[32][132];   // [k][m], +4 pad (16.9 KB)
  __shared__ float Bs[32][132];   // [k][n]          (16.9 KB)
  const int tid = threadIdx.x;
  const int id = blockIdx.x;
  const int xcd = id & 7;
  const int j = id >> 3;               // 0..199 sequential per XCD
  const int m0 = (xcd * 25 + (j >> 3)) * 128;
  const int n0 = (j & 7) * 128;
  const int tx = tid & 31;        // col group (4 cols)
  const int ty = tid >> 5;        // row group (8 rows)
  const int lrow = tid >> 2;      // 0..127
  const int lc8 = (tid & 3) * 8;  // 0,8,16,24

  // hoisted per-thread global pointers
  const float* pA = &A[(size_t)(m0 + lrow) * N_IN + ks + lc8];
  const float* pB = &Bm[(size_t)(n0 + lrow) * N_IN + ks + lc8];

  float acc[8][4];
#pragma unroll
  for (int i = 0; i < 8; i++)
#pragma unroll
    for (int j2 = 0; j2 < 4; j2++) acc[i][j2] = 0.f;

  for (int kk = 0; kk < klen; kk += 32) {
    // stage A tile (128x32) and B tile (128x32): 2 float4 each per thread
    const float4 av0 = *(const float4*)(pA + kk);
    const float4 av1 = *(const float4*)(pA + kk + 4);
    const float4 bv0 = *(const float4*)(pB + kk);
    const float4 bv1 = *(const float4*)(pB + kk + 4);
    As[lc8 + 0][lrow] = av0.x; As[lc8 + 1][lrow] = av0.y;
    As[lc8 + 2][lrow] = av0.z; As[lc8 + 3][lrow] = av0.w;
    As[lc8 + 4][lrow] = av1.x; As[lc8 + 5][lrow] = av1.y;
    As[lc8 + 6][lrow] = av1.z; As[lc8 + 7][lrow] = av1.w;
    Bs[lc8 + 0][lrow] = bv0.x; Bs[lc8 + 1][lrow] = bv0.y;
    Bs[lc8 + 2][lrow] = bv0.z; Bs[lc8 + 3][lrow] = bv0.w;
    Bs[lc8 + 4][lrow] = bv1.x; Bs[lc8 + 5][lrow] = bv1.y;
    Bs[lc8 + 6][lrow] = bv1.z; Bs[lc8 + 7][lrow] = bv1.w;
    __syncthreads();
#pragma unroll
    for (int k = 0; k < 32; k++) {
      float a[8], b[4];
      *(float4*)&a[0] = *(const float4*)&As[k][ty * 8];
      *(float4*)&a[4] = *(const float4*)&As[k][ty * 8 + 4];
      *(float4*)&b[0] = *(const float4*)&Bs[k][tx * 4];
#pragma unroll
      for (int i = 0; i < 8; i++)
#pragma unroll
        for (int j2 = 0; j2 < 4; j2++)
          acc[i][j2] = __builtin_fmaf(a[i], b[j2], acc[i][j2]);
    }
    __syncthreads();
  }
  // epilogue: join with previous panels (one add), bias after last panel
#pragma unroll
  for (int i = 0; i < 8; i++) {
    const int m = m0 + ty * 8 + i;
    const int n1 = n0 + tx * 4;
    float4* cp = (float4*)&C[(size_t)m * N_H + n1];
    float4 v;
    v.x = acc[i][0]; v.y = acc[i][1]; v.z = acc[i][2]; v.w = acc[i][3];
    if (!first) {
      const float4 o = *cp;
      v.x = __fadd_rn(o.x, v.x); v.y = __fadd_rn(o.y, v.y);
      v.z = __fadd_rn(o.z, v.z); v.w = __fadd_rn(o.w, v.w);
    }
    if (last) {
      v.x = __fadd_rn(v.x, bias[n1 + 0]); v.y = __fadd_rn(v.y, bias[n1 + 1]);
      v.z = __fadd_rn(v.z, bias[n1 + 2]); v.w = __fadd_rn(v.w, bias[n1 + 3]);
    }
    *cp = v;
  }
}

// ---------------------------------------------------------------------------
// Scan1: strict numpy op order (no fma): mem = ((0.9*mem) + cur) - reset.
// Spikes -> packed 64-bit ballot masks.
// ---------------------------------------------------------------------------
__global__ __launch_bounds__(256) void scan1_kernel(
    const float* __restrict__ cur1, unsigned long long* __restrict__ spkbits) {
  const int b = blockIdx.x >> 2;
  const int h = (blockIdx.x & 3) * 256 + threadIdx.x;
  const int lane = threadIdx.x & 63;
  const int word = h >> 6;  // 0..15
  float mem = 0.f;
  for (int t = 0; t < T_STEPS; ++t) {
    const float c = cur1[((size_t)t * BATCH + b) * N_H + h];
    const float reset = (mem > 1.0f) ? 1.0f : 0.0f;   // previous mem
    mem = __fsub_rn(__fadd_rn(__fmul_rn(0.9f, mem), c), reset);
    const unsigned long long msk = __ballot(mem > 1.0f);
    if (lane == 0) spkbits[((size_t)t * BATCH + b) * 16 + word] = msk;
  }
}

// ---------------------------------------------------------------------------
// cur2 (parallel over t,b,o): 3-panel k-ascending FMA chains —
// s1=[0,384), s2=[384,768), s3=[768,1024); cur2 = ((s1+s2)+s3) + b2[o].
// ---------------------------------------------------------------------------
__global__ __launch_bounds__(256) void cur2_kernel(
    const unsigned long long* __restrict__ spkbits,
    const float* __restrict__ W2, const float* __restrict__ b2,
    float* __restrict__ cur2) {
  const int g = blockIdx.x * 256 + threadIdx.x;   // ((t*256)+b)*10 + o
  const int tb = g / N_OUT;                       // t*256 + b
  const int o = g - tb * N_OUT;
  unsigned long long w[16];
#pragma unroll
  for (int i = 0; i < 16; i++) w[i] = spkbits[(size_t)tb * 16 + i];
  const float* W2o = &W2[(size_t)o * N_H];
  float s1 = 0.f, s2 = 0.f, s3 = 0.f;
#pragma unroll 8
  for (int h = 0; h < KC; ++h) {
    const float spk = ((w[h >> 6] >> (h & 63)) & 1ull) ? 1.0f : 0.0f;
    s1 = __builtin_fmaf(spk, W2o[h], s1);
  }
#pragma unroll 8
  for (int h = KC; h < 2 * KC; ++h) {
    const float spk = ((w[h >> 6] >> (h & 63)) & 1ull) ? 1.0f : 0.0f;
    s2 = __builtin_fmaf(spk, W2o[h], s2);
  }
#pragma unroll 8
  for (int h = 2 * KC; h < N_H; ++h) {
    const float spk = ((w[h >> 6] >> (h & 63)) & 1ull) ? 1.0f : 0.0f;
    s3 = __builtin_fmaf(spk, W2o[h], s3);
  }
  cur2[g] = __fadd_rn(__fadd_rn(__fadd_rn(s1, s2), s3), b2[o]);
}

// ---------------------------------------------------------------------------
// Scan2: strict mem2 scan over t per (b,o); writes spk2 + final mem2 (f32).
// ---------------------------------------------------------------------------
__global__ __launch_bounds__(256) void scan2_kernel(
    const float* __restrict__ cur2, float* __restrict__ out) {
  const int g = blockIdx.x * 256 + threadIdx.x;   // b*10 + o
  float m = 0.f;
  for (int t = 0; t < T_STEPS; ++t) {
    const float c = cur2[(size_t)t * (BATCH * N_OUT) + g];
    const float reset = (m > 1.0f) ? 1.0f : 0.0f;   // previous mem2
    m = __fsub_rn(__fadd_rn(__fmul_rn(0.9f, m), c), reset);
    out[(size_t)t * (BATCH * N_OUT) + g] = (m > 1.0f) ? 1.0f : 0.0f;
  }
  out[(size_t)T_STEPS * (BATCH * N_OUT) + g] = m;
}

// ---------------------------------------------------------------------------
extern "C" void kernel_launch(void* const* d_in, const int* in_sizes, int n_in,
                              void* d_out, int out_size, void* d_ws, size_t ws_size,
                              hipStream_t stream) {
  const float* x  = (const float*)d_in[0];   // [T, B, N_IN]  f32
  const float* W1 = (const float*)d_in[1];   // [N_H, N_IN]   f32
  const float* b1 = (const float*)d_in[2];   // [N_H]         f32
  const float* W2 = (const float*)d_in[3];   // [N_OUT, N_H]  f32
  const float* b2 = (const float*)d_in[4];   // [N_OUT]       f32
  float* out = (float*)d_out;  // f32: spk2[100,256,10] ++ mem2[256,10]

  // ws: cur1 f32 (104.9MB) | bits (3.3MB) | cur2 f32 (1.02MB)
  char* p = (char*)d_ws;
  float* cur1 = (float*)p;                           p += (size_t)M_TOT * N_H * 4;
  unsigned long long* bits = (unsigned long long*)p; p += (size_t)M_TOT * 16 * 8;
  float* cur2 = (float*)p;

  const int nblk = (M_TOT / 128) * (N_H / 128);   // 1600
  for (int ks = 0; ks < N_IN; ks += KC) {
    const int klen = (ks + KC <= N_IN) ? KC : (N_IN - ks);
    gemm1_panel<<<nblk, 512, 0, stream>>>(x, W1, b1, cur1, ks, klen,
                                          ks == 0 ? 1 : 0,
                                          (ks + klen == N_IN) ? 1 : 0);
  }
  scan1_kernel<<<BATCH * (N_H / 256), 256, 0, stream>>>(cur1, bits);
  cur2_kernel<<<(M_TOT * N_OUT) / 256, 256, 0, stream>>>(bits, W2, b2, cur2);
  scan2_kernel<<<(BATCH * N_OUT) / 256, 256, 0, stream>>>(cur2, out);
}